// Round 1
// baseline (2066.605 us; speedup 1.0000x reference)
//
#include <hip/hip_runtime.h>

#define N_NODES 50000
#define E_EDGES 800000
#define NG 16
#define DD 64
#define HH 128

typedef __attribute__((ext_vector_type(8))) __bf16 bf16x8;
typedef __attribute__((ext_vector_type(4))) float f32x4;
typedef unsigned int uint;
typedef __attribute__((ext_vector_type(4))) uint uint4v;

#define MFMA16(a,b,c) __builtin_amdgcn_mfma_f32_16x16x32_bf16((a),(b),(c),0,0,0)

__device__ __forceinline__ unsigned short f2bf(float f){
  uint u = __builtin_bit_cast(uint, f);
  u += 0x7fffu + ((u >> 16) & 1u);
  return (unsigned short)(u >> 16);
}
__device__ __forceinline__ uint pk2(float a, float b){
  return (uint)f2bf(a) | ((uint)f2bf(b) << 16);
}

// LDS tile helpers: row pitch 256 B, XOR swizzle on 16B chunks within row.
__device__ __forceinline__ bf16x8 ldfrag(const char* base, int row, int byteoff){
  uint4v v = *(const uint4v*)(base + row*256 + (byteoff ^ ((row & 7) << 4)));
  return __builtin_bit_cast(bf16x8, v);
}
__device__ __forceinline__ void st_h(char* base, int row, int col, float v){
  *(unsigned short*)(base + row*256 + ((col*2) ^ ((row & 7) << 4))) = f2bf(v);
}
__device__ __forceinline__ void st_chunk(char* base, int row, int c16, uint4v v){
  *(uint4v*)(base + row*256 + ((c16*16) ^ ((row & 7) << 4))) = v;
}

// Stage packed bf16 weight Wt [Nout][Ktot] (row-major, transposed weight) into sB,
// taking 128 k-columns starting at koff. 16B chunks, swizzled.
__device__ __forceinline__ void stage_b(char* sB, const unsigned short* wt,
                                        int Nout, int Ktot, int koff, int t){
  for (int task = t; task < Nout*16; task += 256){
    int n = task >> 4, c = task & 15;
    uint4v v = *(const uint4v*)(wt + (long)n*Ktot + koff + c*8);
    st_chunk(sB, n, c, v);
  }
}

template<int NT>
__device__ __forceinline__ void gemm_acc(const char* Abase, const char* Bbase,
                                         int wv, int l15, int lhi, f32x4* acc){
  #pragma unroll
  for (int kt = 0; kt < 4; ++kt){
    bf16x8 a = ldfrag(Abase, wv*16 + l15, kt*64 + lhi*16);
    #pragma unroll
    for (int n = 0; n < NT; ++n){
      bf16x8 bb = ldfrag(Bbase, n*16 + l15, kt*64 + lhi*16);
      acc[n] = MFMA16(a, bb, acc[n]);
    }
  }
}

template<int NT, bool RELU>
__device__ __forceinline__ void epi_lds(char* dst, const f32x4* acc, const float* bias,
                                        int wv, int l15, int lhi){
  #pragma unroll
  for (int n = 0; n < NT; ++n){
    float bv = bias[n*16 + l15];
    #pragma unroll
    for (int j = 0; j < 4; ++j){
      int r = wv*16 + lhi*4 + j;
      float v = acc[n][j] + bv;
      if (RELU) v = fmaxf(v, 0.f);
      st_h(dst, r, n*16 + l15, v);
    }
  }
}

// ---------------- weight pack: fp32 [L][K][N] -> bf16 transposed [L][N][K] ----------
__global__ void pack_weights(const float* __restrict__ e1, const float* __restrict__ e2,
                             const float* __restrict__ e3, const float* __restrict__ n11,
                             const float* __restrict__ n12, const float* __restrict__ n21,
                             const float* __restrict__ n22, unsigned short* __restrict__ out){
  int idx = blockIdx.x * 256 + threadIdx.x;   // 2*131072 total
  int l = idx / 131072, r = idx % 131072;
  const float* src; int K, N, off;
  if      (r <  32768){ src = e1;  K = 256; N = 128; off = 0; }
  else if (r <  49152){ src = e2;  K = 128; N = 128; off = 32768; }
  else if (r <  57344){ src = e3;  K = 128; N = 64;  off = 49152; }
  else if (r <  73728){ src = n11; K = 128; N = 128; off = 57344; }
  else if (r <  90112){ src = n12; K = 128; N = 128; off = 73728; }
  else if (r < 122880){ src = n21; K = 256; N = 128; off = 90112; }
  else                { src = n22; K = 128; N = 64;  off = 122880; }
  int q = r - off; int k = q / N; int n = q % N;
  out[(long)l*131072 + off + n*K + k] = f2bf(src[(long)l*K*N + q]);
}

// ---------------- counts ----------------
__global__ void count_kernel(const int* __restrict__ edge_index, const int* __restrict__ batch,
                             float* __restrict__ cnt_col, float* __restrict__ cnt_eb){
  __shared__ float h[NG];
  int t = threadIdx.x;
  if (t < NG) h[t] = 0.f;
  __syncthreads();
  int e = blockIdx.x * 256 + t;
  if (e < E_EDGES){
    atomicAdd(cnt_col + edge_index[E_EDGES + e], 1.f);
    atomicAdd(&h[batch[edge_index[e]]], 1.f);
  }
  __syncthreads();
  if (t < NG) atomicAdd(cnt_eb + t, h[t]);
}
__global__ void count_nodes_kernel(const int* __restrict__ batch, float* __restrict__ cnt_b){
  __shared__ float h[NG];
  int t = threadIdx.x;
  if (t < NG) h[t] = 0.f;
  __syncthreads();
  int n = blockIdx.x * 256 + t;
  if (n < N_NODES) atomicAdd(&h[batch[n]], 1.f);
  __syncthreads();
  if (t < NG) atomicAdd(cnt_b + t, h[t]);
}

// ---------------- edge kernel: edge MLP + node-MLP1 + scatter ----------------
__global__ __launch_bounds__(256, 2) void edge_kernel(
    const float* __restrict__ x_cur, const float* __restrict__ e_cur,
    const float* __restrict__ u_cur, const float* __restrict__ e_resid,
    const int* __restrict__ edge_index, const int* __restrict__ batch,
    const unsigned short* __restrict__ w_e1, const unsigned short* __restrict__ w_e2,
    const unsigned short* __restrict__ w_e3, const unsigned short* __restrict__ w_n11,
    const unsigned short* __restrict__ w_n12,
    const float* __restrict__ b_e1, const float* __restrict__ b_e2,
    const float* __restrict__ b_e3, const float* __restrict__ b_n11,
    const float* __restrict__ b_n12,
    float* __restrict__ e_out, float* __restrict__ agg_sum, float* __restrict__ e_agg,
    int has_resid)
{
  __shared__ __align__(16) char sA[16384];   // 64 rows x 128 bf16 (A half / H2 / A2)
  __shared__ __align__(16) char sB[32768];   // 128 rows x 128 bf16 (weights)
  __shared__ __align__(16) char sH[16384];   // 64 rows x 128 bf16 (H1 / H3)
  __shared__ int sRow[64], sCol[64], sEb[64];
  __shared__ float sEagg[NG*DD];

  const int t = threadIdx.x;
  const int wv = t >> 6, ln = t & 63, l15 = ln & 15, lhi = ln >> 4;
  const int ebase = blockIdx.x * 64;

  if (t < 64){
    int r = edge_index[ebase + t];
    int c = edge_index[E_EDGES + ebase + t];
    sRow[t] = r; sCol[t] = c; sEb[t] = batch[r];
  }
  for (int i = t; i < NG*DD; i += 256) sEagg[i] = 0.f;
  __syncthreads();

  // ---- GEMM1: concat[x_row,x_col,e,u_eb] (256) x e_w1 -> 128, two K-halves ----
  f32x4 acc1[8];
  #pragma unroll
  for (int n = 0; n < 8; ++n) acc1[n] = f32x4{0.f,0.f,0.f,0.f};

  for (int half = 0; half < 2; ++half){
    for (int task = t; task < 1024; task += 256){
      int r = task >> 4, c = task & 15;
      const float* src;
      if (half == 0) src = (c < 8) ? (x_cur + (long)sRow[r]*DD + c*8)
                                   : (x_cur + (long)sCol[r]*DD + (c-8)*8);
      else           src = (c < 8) ? (e_cur + (long)(ebase + r)*DD + c*8)
                                   : (u_cur + (long)sEb[r]*DD + (c-8)*8);
      float4 lo = *(const float4*)src;
      float4 hi = *(const float4*)(src + 4);
      uint4v v; v.x = pk2(lo.x, lo.y); v.y = pk2(lo.z, lo.w);
      v.z = pk2(hi.x, hi.y); v.w = pk2(hi.z, hi.w);
      st_chunk(sA, r, c, v);
    }
    stage_b(sB, w_e1, 128, 256, half*128, t);
    __syncthreads();
    gemm_acc<8>(sA, sB, wv, l15, lhi, acc1);
    __syncthreads();
  }
  epi_lds<8, true>(sH, acc1, b_e1, wv, l15, lhi);
  stage_b(sB, w_e2, 128, 128, 0, t);
  __syncthreads();

  // ---- GEMM2: H1 x e_w2 -> H2 (into sA) ----
  f32x4 acc2[8];
  #pragma unroll
  for (int n = 0; n < 8; ++n) acc2[n] = f32x4{0.f,0.f,0.f,0.f};
  gemm_acc<8>(sH, sB, wv, l15, lhi, acc2);
  __syncthreads();
  epi_lds<8, true>(sA, acc2, b_e2, wv, l15, lhi);
  stage_b(sB, w_e3, 64, 128, 0, t);
  __syncthreads();

  // ---- GEMM3: H2 x e_w3 -> e_new (64) ----
  f32x4 acc3[4];
  #pragma unroll
  for (int n = 0; n < 4; ++n) acc3[n] = f32x4{0.f,0.f,0.f,0.f};
  gemm_acc<4>(sA, sB, wv, l15, lhi, acc3);

  float enew[4][4];
  #pragma unroll
  for (int n = 0; n < 4; ++n){
    float bv = b_e3[n*16 + l15];
    #pragma unroll
    for (int j = 0; j < 4; ++j){
      int r = wv*16 + lhi*4 + j;
      int col = n*16 + l15;
      float v = acc3[n][j] + bv;
      enew[n][j] = v;
      long eg = (long)(ebase + r)*DD + col;
      e_out[eg] = has_resid ? (v + e_resid[eg]) : v;
      atomicAdd(&sEagg[sEb[r]*DD + col], v);
    }
  }
  __syncthreads();   // all GEMM3 reads of sA/sB done

  // ---- A2 = concat[x_row, e_new] into sA; stage n1_w1 ----
  #pragma unroll
  for (int n = 0; n < 4; ++n){
    #pragma unroll
    for (int j = 0; j < 4; ++j){
      int r = wv*16 + lhi*4 + j;
      st_h(sA, r, 64 + n*16 + l15, enew[n][j]);
    }
  }
  for (int task = t; task < 512; task += 256){
    int r = task >> 3, c = task & 7;
    const float* src = x_cur + (long)sRow[r]*DD + c*8;
    float4 lo = *(const float4*)src;
    float4 hi = *(const float4*)(src + 4);
    uint4v v; v.x = pk2(lo.x, lo.y); v.y = pk2(lo.z, lo.w);
    v.z = pk2(hi.x, hi.y); v.w = pk2(hi.z, hi.w);
    st_chunk(sA, r, c, v);
  }
  stage_b(sB, w_n11, 128, 128, 0, t);
  __syncthreads();

  // ---- GEMM4: A2 x n1_w1 -> H3 (sH) ----
  f32x4 acc4[8];
  #pragma unroll
  for (int n = 0; n < 8; ++n) acc4[n] = f32x4{0.f,0.f,0.f,0.f};
  gemm_acc<8>(sA, sB, wv, l15, lhi, acc4);
  __syncthreads();
  epi_lds<8, true>(sH, acc4, b_n11, wv, l15, lhi);
  stage_b(sB, w_n12, 128, 128, 0, t);
  __syncthreads();

  // ---- GEMM5: H3 x n1_w2 -> se; scatter to agg_sum[col] ----
  f32x4 acc5[8];
  #pragma unroll
  for (int n = 0; n < 8; ++n) acc5[n] = f32x4{0.f,0.f,0.f,0.f};
  gemm_acc<8>(sH, sB, wv, l15, lhi, acc5);

  #pragma unroll
  for (int n = 0; n < 8; ++n){
    float bv = b_n12[n*16 + l15];
    #pragma unroll
    for (int j = 0; j < 4; ++j){
      int r = wv*16 + lhi*4 + j;
      float v = acc5[n][j] + bv;
      atomicAdd(agg_sum + (long)sCol[r]*HH + n*16 + l15, v);
    }
  }
  // flush per-block e_agg partial (sEagg writes all happened before an earlier barrier)
  for (int i = t; i < NG*DD; i += 256) atomicAdd(e_agg + i, sEagg[i]);
}

// ---------------- node kernel: node-MLP2 ----------------
__global__ __launch_bounds__(256, 2) void node_kernel(
    const float* __restrict__ x_cur, const float* __restrict__ u_cur,
    const float* __restrict__ x_resid, const int* __restrict__ batch,
    const float* __restrict__ agg_sum, const float* __restrict__ cnt_col,
    const unsigned short* __restrict__ w_n21, const unsigned short* __restrict__ w_n22,
    const float* __restrict__ b_n21, const float* __restrict__ b_n22,
    float* __restrict__ x_out, float* __restrict__ n_agg, int has_resid)
{
  __shared__ __align__(16) char sA[16384];
  __shared__ __align__(16) char sB[32768];
  __shared__ __align__(16) char sH[16384];
  __shared__ int sBat[64];
  __shared__ float sRinv[64];
  __shared__ float sNagg[NG*DD];

  const int t = threadIdx.x;
  const int wv = t >> 6, ln = t & 63, l15 = ln & 15, lhi = ln >> 4;
  const int n0 = blockIdx.x * 64;

  if (t < 64){
    int nd = n0 + t;
    int ok = nd < N_NODES;
    sBat[t] = ok ? batch[nd] : 0;
    float c = ok ? cnt_col[nd] : 1.f;
    sRinv[t] = 1.f / fmaxf(c, 1.f);
  }
  for (int i = t; i < NG*DD; i += 256) sNagg[i] = 0.f;
  __syncthreads();

  f32x4 acc[8];
  #pragma unroll
  for (int n = 0; n < 8; ++n) acc[n] = f32x4{0.f,0.f,0.f,0.f};

  for (int half = 0; half < 2; ++half){
    for (int task = t; task < 1024; task += 256){
      int r = task >> 4, c = task & 15;
      int nd = n0 + r;
      bool ok = nd < N_NODES;
      float scale = 1.f;
      const float* src;
      if (half == 0){
        if (c < 8) src = x_cur + (long)nd*DD + c*8;
        else { src = agg_sum + (long)nd*HH + (c-8)*8; scale = sRinv[r]; }
      } else {
        if (c < 8){ src = agg_sum + (long)nd*HH + 64 + c*8; scale = sRinv[r]; }
        else src = u_cur + (long)sBat[r]*DD + (c-8)*8;
      }
      float4 lo = {0.f,0.f,0.f,0.f}, hi = {0.f,0.f,0.f,0.f};
      if (ok){ lo = *(const float4*)src; hi = *(const float4*)(src + 4); }
      uint4v v; v.x = pk2(lo.x*scale, lo.y*scale); v.y = pk2(lo.z*scale, lo.w*scale);
      v.z = pk2(hi.x*scale, hi.y*scale); v.w = pk2(hi.z*scale, hi.w*scale);
      st_chunk(sA, r, c, v);
    }
    stage_b(sB, w_n21, 128, 256, half*128, t);
    __syncthreads();
    gemm_acc<8>(sA, sB, wv, l15, lhi, acc);
    __syncthreads();
  }
  epi_lds<8, true>(sH, acc, b_n21, wv, l15, lhi);
  stage_b(sB, w_n22, 64, 128, 0, t);
  __syncthreads();

  f32x4 acc2[4];
  #pragma unroll
  for (int n = 0; n < 4; ++n) acc2[n] = f32x4{0.f,0.f,0.f,0.f};
  gemm_acc<4>(sH, sB, wv, l15, lhi, acc2);

  #pragma unroll
  for (int n = 0; n < 4; ++n){
    float bv = b_n22[n*16 + l15];
    #pragma unroll
    for (int j = 0; j < 4; ++j){
      int r = wv*16 + lhi*4 + j;
      int nd = n0 + r;
      if (nd < N_NODES){
        int col = n*16 + l15;
        float v = acc2[n][j] + bv;
        long xg = (long)nd*DD + col;
        x_out[xg] = has_resid ? (v + x_resid[xg]) : v;
        atomicAdd(&sNagg[sBat[r]*DD + col], v);
      }
    }
  }
  __syncthreads();
  for (int i = t; i < NG*DD; i += 256) atomicAdd(n_agg + i, sNagg[i]);
}

// ---------------- global (per-graph) MLP, fp32 ----------------
__global__ void global_kernel(const float* __restrict__ u_cur, const float* __restrict__ n_agg,
                              const float* __restrict__ e_agg, const float* __restrict__ cnt_b,
                              const float* __restrict__ cnt_e,
                              const float* __restrict__ g_w1, const float* __restrict__ g_b1,
                              const float* __restrict__ g_w2, const float* __restrict__ g_b2,
                              const float* __restrict__ u_resid, float* __restrict__ u_out,
                              int has_resid)
{
  int g = blockIdx.x, t = threadIdx.x;   // 192 threads
  __shared__ float uh[192];
  __shared__ float hb[128];
  float v;
  if (t < 64)       v = u_cur[g*64 + t];
  else if (t < 128) v = n_agg[g*64 + (t-64)] / fmaxf(cnt_b[g], 1.f);
  else              v = e_agg[g*64 + (t-128)] / fmaxf(cnt_e[g], 1.f);
  uh[t] = v;
  __syncthreads();
  if (t < 128){
    float s = g_b1[t];
    for (int k = 0; k < 192; ++k) s += uh[k] * g_w1[k*128 + t];
    hb[t] = fmaxf(s, 0.f);
  }
  __syncthreads();
  if (t < 64){
    float s = g_b2[t];
    for (int k = 0; k < 128; ++k) s += hb[k] * g_w2[k*64 + t];
    if (has_resid) s += u_resid[g*64 + t];
    u_out[g*64 + t] = s;
  }
}

extern "C" void kernel_launch(void* const* d_in, const int* in_sizes, int n_in,
                              void* d_out, int out_size, void* d_ws, size_t ws_size,
                              hipStream_t stream)
{
  const float* x0   = (const float*)d_in[0];
  const float* e0   = (const float*)d_in[1];
  const float* u0   = (const float*)d_in[2];
  const float* e_w1 = (const float*)d_in[3];
  const float* e_b1 = (const float*)d_in[4];
  const float* e_w2 = (const float*)d_in[5];
  const float* e_b2 = (const float*)d_in[6];
  const float* e_w3 = (const float*)d_in[7];
  const float* e_b3 = (const float*)d_in[8];
  const float* n1_w1 = (const float*)d_in[9];
  const float* n1_b1 = (const float*)d_in[10];
  const float* n1_w2 = (const float*)d_in[11];
  const float* n1_b2 = (const float*)d_in[12];
  const float* n2_w1 = (const float*)d_in[13];
  const float* n2_b1 = (const float*)d_in[14];
  const float* n2_w2 = (const float*)d_in[15];
  const float* n2_b2 = (const float*)d_in[16];
  const float* g_w1 = (const float*)d_in[17];
  const float* g_b1 = (const float*)d_in[18];
  const float* g_w2 = (const float*)d_in[19];
  const float* g_b2 = (const float*)d_in[20];
  const int* edge_index = (const int*)d_in[21];
  const int* batch      = (const int*)d_in[22];

  float* out_x = (float*)d_out;
  float* out_e = out_x + (long)N_NODES*DD;
  float* out_u = out_e + (long)E_EDGES*DD;

  char* ws = (char*)d_ws;
  float* agg_sum = (float*)ws;                            // 25,600,000 B
  float* cnt_col = (float*)(ws + 25600000);               // 200,000 B
  float* cnt_eb  = (float*)(ws + 25800000);               // 64 B
  float* cnt_b   = (float*)(ws + 25800064);               // 64 B
  float* e_agg   = (float*)(ws + 25800128);               // 4096 B
  float* n_agg   = (float*)(ws + 25804224);               // 4096 B
  unsigned short* packed = (unsigned short*)(ws + 25808320); // 524,288 B

  (void)hipMemsetAsync(cnt_col, 0, 200128, stream);  // cnt_col + cnt_eb + cnt_b
  pack_weights<<<1024, 256, 0, stream>>>(e_w1, e_w2, e_w3, n1_w1, n1_w2, n2_w1, n2_w2, packed);
  count_kernel<<<3125, 256, 0, stream>>>(edge_index, batch, cnt_col, cnt_eb);
  count_nodes_kernel<<<196, 256, 0, stream>>>(batch, cnt_b);

  const float* xc = x0;
  const float* ec = e0;
  const float* uc = u0;
  for (int l = 0; l < 2; ++l){
    (void)hipMemsetAsync(agg_sum, 0, (size_t)N_NODES*HH*4, stream);
    (void)hipMemsetAsync(e_agg, 0, 4096, stream);
    (void)hipMemsetAsync(n_agg, 0, 4096, stream);
    const unsigned short* P = packed + (long)l*131072;
    edge_kernel<<<E_EDGES/64, 256, 0, stream>>>(
        xc, ec, uc, e0, edge_index, batch,
        P + 0, P + 32768, P + 49152, P + 57344, P + 73728,
        e_b1 + l*128, e_b2 + l*128, e_b3 + l*64, n1_b1 + l*128, n1_b2 + l*128,
        out_e, agg_sum, e_agg, l == 1);
    node_kernel<<<782, 256, 0, stream>>>(
        xc, uc, x0, batch, agg_sum, cnt_col,
        P + 90112, P + 122880, n2_b1 + l*128, n2_b2 + l*64,
        out_x, n_agg, l == 1);
    global_kernel<<<NG, 192, 0, stream>>>(
        uc, n_agg, e_agg, cnt_b, cnt_eb,
        g_w1 + l*192*128, g_b1 + l*128, g_w2 + l*128*64, g_b2 + l*64,
        u0, out_u, l == 1);
    xc = out_x; ec = out_e; uc = out_u;
  }
}

// Round 2
// 1804.736 us; speedup vs baseline: 1.1451x; 1.1451x over previous
//
#include <hip/hip_runtime.h>

#define N_NODES 50000
#define E_EDGES 800000
#define NG 16
#define DD 64
#define HH 128
#define NB_SCAN 49

typedef __attribute__((ext_vector_type(8))) __bf16 bf16x8;
typedef __attribute__((ext_vector_type(4))) float f32x4;
typedef unsigned int uint;
typedef unsigned short ushort;
typedef __attribute__((ext_vector_type(4))) uint uint4v;

#define MFMA16(a,b,c) __builtin_amdgcn_mfma_f32_16x16x32_bf16((a),(b),(c),0,0,0)

__device__ __forceinline__ ushort f2bf(float f){
  uint u = __builtin_bit_cast(uint, f);
  u += 0x7fffu + ((u >> 16) & 1u);
  return (ushort)(u >> 16);
}
__device__ __forceinline__ uint pk2(float a, float b){
  return (uint)f2bf(a) | ((uint)f2bf(b) << 16);
}
__device__ __forceinline__ float bflo(uint u){ return __builtin_bit_cast(float, u << 16); }
__device__ __forceinline__ float bfhi(uint u){ return __builtin_bit_cast(float, u & 0xffff0000u); }

// LDS tile: row pitch 256 B, XOR swizzle on 16B chunks within row.
__device__ __forceinline__ bf16x8 ldfrag(const char* base, int row, int byteoff){
  uint4v v = *(const uint4v*)(base + row*256 + (byteoff ^ ((row & 7) << 4)));
  return __builtin_bit_cast(bf16x8, v);
}
__device__ __forceinline__ uint4v ld_chunk(const char* base, int row, int c16){
  return *(const uint4v*)(base + row*256 + ((c16*16) ^ ((row & 7) << 4)));
}
__device__ __forceinline__ void st_h(char* base, int row, int col, float v){
  *(ushort*)(base + row*256 + ((col*2) ^ ((row & 7) << 4))) = f2bf(v);
}
__device__ __forceinline__ void st_chunk(char* base, int row, int c16, uint4v v){
  *(uint4v*)(base + row*256 + ((c16*16) ^ ((row & 7) << 4))) = v;
}
__device__ __forceinline__ void pack16(char* dst, int r, int c16, const float* src){
  float4 lo = *(const float4*)src;
  float4 hi = *(const float4*)(src + 4);
  uint4v v; v.x = pk2(lo.x, lo.y); v.y = pk2(lo.z, lo.w);
  v.z = pk2(hi.x, hi.y); v.w = pk2(hi.z, hi.w);
  st_chunk(dst, r, c16, v);
}

__device__ __forceinline__ void stage_b(char* sB, const ushort* wt,
                                        int Nout, int Ktot, int koff, int t, int stride){
  for (int task = t; task < Nout*16; task += stride){
    int n = task >> 4, c = task & 15;
    uint4v v = *(const uint4v*)(wt + (long)n*Ktot + koff + c*8);
    st_chunk(sB, n, c, v);
  }
}

// 8-wave layout: wave = (mw = wv&3) row-group x (nh = wv>>2) col-half.
__device__ __forceinline__ void gemmN4(const char* A, const char* B,
                                       int mw, int nh, int l15, int lhi, f32x4* acc){
  #pragma unroll
  for (int kt = 0; kt < 4; ++kt){
    bf16x8 a = ldfrag(A, mw*16 + l15, kt*64 + lhi*16);
    #pragma unroll
    for (int n = 0; n < 4; ++n){
      bf16x8 bb = ldfrag(B, (nh*4 + n)*16 + l15, kt*64 + lhi*16);
      acc[n] = MFMA16(a, bb, acc[n]);
    }
  }
}
template<bool RELU>
__device__ __forceinline__ void epiN4(char* dst, const f32x4* acc, const float* bias,
                                      int mw, int nh, int l15, int lhi){
  #pragma unroll
  for (int n = 0; n < 4; ++n){
    int col = nh*64 + n*16 + l15;
    float bv = bias[col];
    #pragma unroll
    for (int j = 0; j < 4; ++j){
      int r = mw*16 + lhi*4 + j;
      float v = acc[n][j] + bv;
      if (RELU) v = fmaxf(v, 0.f);
      st_h(dst, r, col, v);
    }
  }
}

// 4-wave helpers (node kernel): wave wv owns rows wv*16, all 8 n-frags.
template<int NT>
__device__ __forceinline__ void gemm_acc(const char* A, const char* B,
                                         int wv, int l15, int lhi, f32x4* acc){
  #pragma unroll
  for (int kt = 0; kt < 4; ++kt){
    bf16x8 a = ldfrag(A, wv*16 + l15, kt*64 + lhi*16);
    #pragma unroll
    for (int n = 0; n < NT; ++n){
      bf16x8 bb = ldfrag(B, n*16 + l15, kt*64 + lhi*16);
      acc[n] = MFMA16(a, bb, acc[n]);
    }
  }
}
template<int NT, bool RELU>
__device__ __forceinline__ void epi_lds(char* dst, const f32x4* acc, const float* bias,
                                        int wv, int l15, int lhi){
  #pragma unroll
  for (int n = 0; n < NT; ++n){
    float bv = bias[n*16 + l15];
    #pragma unroll
    for (int j = 0; j < 4; ++j){
      int r = wv*16 + lhi*4 + j;
      float v = acc[n][j] + bv;
      if (RELU) v = fmaxf(v, 0.f);
      st_h(dst, r, n*16 + l15, v);
    }
  }
}

// ---------------- weight pack: fp32 [L][K][N] -> bf16 transposed [L][N][K] ----------
__global__ void pack_weights(const float* __restrict__ e1, const float* __restrict__ e2,
                             const float* __restrict__ e3, const float* __restrict__ n11,
                             const float* __restrict__ n12, const float* __restrict__ n21,
                             const float* __restrict__ n22, ushort* __restrict__ out){
  int idx = blockIdx.x * 256 + threadIdx.x;
  int l = idx / 131072, r = idx % 131072;
  const float* src; int K, N, off;
  if      (r <  32768){ src = e1;  K = 256; N = 128; off = 0; }
  else if (r <  49152){ src = e2;  K = 128; N = 128; off = 32768; }
  else if (r <  57344){ src = e3;  K = 128; N = 64;  off = 49152; }
  else if (r <  73728){ src = n11; K = 128; N = 128; off = 57344; }
  else if (r <  90112){ src = n12; K = 128; N = 128; off = 73728; }
  else if (r < 122880){ src = n21; K = 256; N = 128; off = 90112; }
  else                { src = n22; K = 128; N = 64;  off = 122880; }
  int q = r - off; int k = q / N; int n = q % N;
  out[(long)l*131072 + off + n*K + k] = f2bf(src[(long)l*K*N + q]);
}

// ---------------- counts / CSR ----------------
__global__ void hist_kernel(const int* __restrict__ edge_index, const int* __restrict__ batch,
                            int* __restrict__ deg, float* __restrict__ cnt_eb){
  __shared__ float h[NG];
  int t = threadIdx.x;
  if (t < NG) h[t] = 0.f;
  __syncthreads();
  int e = blockIdx.x * 256 + t;
  if (e < E_EDGES){
    atomicAdd(deg + edge_index[E_EDGES + e], 1);
    atomicAdd(&h[batch[edge_index[e]]], 1.f);
  }
  __syncthreads();
  if (t < NG) atomicAdd(cnt_eb + t, h[t]);
}
__global__ void count_nodes_kernel(const int* __restrict__ batch, float* __restrict__ cnt_b){
  __shared__ float h[NG];
  int t = threadIdx.x;
  if (t < NG) h[t] = 0.f;
  __syncthreads();
  int n = blockIdx.x * 256 + t;
  if (n < N_NODES) atomicAdd(&h[batch[n]], 1.f);
  __syncthreads();
  if (t < NG) atomicAdd(cnt_b + t, h[t]);
}
__global__ void scan_a(const int* __restrict__ deg, int* __restrict__ bsum){
  __shared__ int red[1024];
  int i = blockIdx.x*1024 + threadIdx.x;
  red[threadIdx.x] = (i < N_NODES) ? deg[i] : 0;
  __syncthreads();
  for (int s = 512; s > 0; s >>= 1){
    if ((int)threadIdx.x < s) red[threadIdx.x] += red[threadIdx.x + s];
    __syncthreads();
  }
  if (threadIdx.x == 0) bsum[blockIdx.x] = red[0];
}
__global__ void scan_b(const int* __restrict__ bsum, int* __restrict__ bbase){
  if (threadIdx.x == 0){
    int run = 0;
    for (int b = 0; b < NB_SCAN; ++b){ int v = bsum[b]; bbase[b] = run; run += v; }
  }
}
__global__ void scan_c(const int* __restrict__ deg, const int* __restrict__ bbase,
                       int* __restrict__ off, int* __restrict__ cursor){
  __shared__ int sc[1024];
  int i = blockIdx.x*1024 + threadIdx.x;
  int v = (i < N_NODES) ? deg[i] : 0;
  sc[threadIdx.x] = v;
  __syncthreads();
  for (int d = 1; d < 1024; d <<= 1){
    int add = ((int)threadIdx.x >= d) ? sc[threadIdx.x - d] : 0;
    __syncthreads();
    sc[threadIdx.x] += add;
    __syncthreads();
  }
  if (i < N_NODES){
    int ex = sc[threadIdx.x] - v + bbase[blockIdx.x];
    off[i] = ex; cursor[i] = ex;
  }
}
__global__ void fill_kernel(const int* __restrict__ edge_index, int* __restrict__ cursor,
                            int* __restrict__ pos){
  int e = blockIdx.x*256 + threadIdx.x;
  if (e < E_EDGES){
    int c = edge_index[E_EDGES + e];
    pos[e] = atomicAdd(&cursor[c], 1);
  }
}

// ---------------- edge kernel: edge MLP + node-MLP1, 8 waves / 64 edges ----------------
template<bool CSR>
__global__ __launch_bounds__(512, 4) void edge_kernel(
    const float* __restrict__ x_cur, const float* __restrict__ e_cur,
    const float* __restrict__ u_cur, const float* __restrict__ e_resid,
    const int* __restrict__ edge_index, const int* __restrict__ batch,
    const int* __restrict__ pos_arr,
    const ushort* __restrict__ w_e1, const ushort* __restrict__ w_e2,
    const ushort* __restrict__ w_e3, const ushort* __restrict__ w_n11,
    const ushort* __restrict__ w_n12,
    const float* __restrict__ b_e1, const float* __restrict__ b_e2,
    const float* __restrict__ b_e3, const float* __restrict__ b_n11,
    const float* __restrict__ b_n12,
    float* __restrict__ e_out, ushort* __restrict__ se_buf,
    float* __restrict__ agg_sum, float* __restrict__ e_agg, int has_resid)
{
  __shared__ __align__(16) char sA[16384];
  __shared__ __align__(16) char sB[32768];
  __shared__ __align__(16) char sH[16384];
  __shared__ int sRow[64], sCol[64], sEb[64];
  __shared__ float sEagg[NG*DD];

  const int t = threadIdx.x;                 // 0..511
  const int wv = t >> 6, ln = t & 63, l15 = ln & 15, lhi = ln >> 4;
  const int mw = wv & 3, nh = wv >> 2;
  const int ebase = blockIdx.x * 64;

  if (t < 64){
    int r = edge_index[ebase + t];
    sRow[t] = r; sCol[t] = edge_index[E_EDGES + ebase + t]; sEb[t] = batch[r];
  }
  for (int i = t; i < NG*DD; i += 512) sEagg[i] = 0.f;
  __syncthreads();

  // ---- GEMM1: concat[x_row,x_col,e,u_eb] (K=256) x e_w1 -> 128 ----
  f32x4 acc1[4];
  #pragma unroll
  for (int n = 0; n < 4; ++n) acc1[n] = f32x4{0.f,0.f,0.f,0.f};
  for (int kh = 0; kh < 2; ++kh){
    for (int task = t; task < 1024; task += 512){
      int r = task >> 4, c = task & 15;
      const float* src;
      if (kh == 0) src = (c < 8) ? (x_cur + (long)sRow[r]*DD + c*8)
                                 : (x_cur + (long)sCol[r]*DD + (c-8)*8);
      else         src = (c < 8) ? (e_cur + (long)(ebase + r)*DD + c*8)
                                 : (u_cur + (long)sEb[r]*DD + (c-8)*8);
      pack16(sA, r, c, src);
    }
    stage_b(sB, w_e1, 128, 256, kh*128, t, 512);
    __syncthreads();
    gemmN4(sA, sB, mw, nh, l15, lhi, acc1);
    __syncthreads();
  }
  epiN4<true>(sH, acc1, b_e1, mw, nh, l15, lhi);
  stage_b(sB, w_e2, 128, 128, 0, t, 512);
  __syncthreads();

  // ---- GEMM2 ----
  f32x4 acc2[4];
  #pragma unroll
  for (int n = 0; n < 4; ++n) acc2[n] = f32x4{0.f,0.f,0.f,0.f};
  gemmN4(sH, sB, mw, nh, l15, lhi, acc2);
  __syncthreads();
  epiN4<true>(sA, acc2, b_e2, mw, nh, l15, lhi);
  stage_b(sB, w_e3, 64, 128, 0, t, 512);
  __syncthreads();

  // ---- GEMM3: N=64; wave covers cols nh*32 + n*16, n in {0,1} ----
  f32x4 acc3[2];
  acc3[0] = f32x4{0.f,0.f,0.f,0.f}; acc3[1] = f32x4{0.f,0.f,0.f,0.f};
  #pragma unroll
  for (int kt = 0; kt < 4; ++kt){
    bf16x8 a = ldfrag(sA, mw*16 + l15, kt*64 + lhi*16);
    #pragma unroll
    for (int n = 0; n < 2; ++n){
      bf16x8 bb = ldfrag(sB, (nh*2 + n)*16 + l15, kt*64 + lhi*16);
      acc3[n] = MFMA16(a, bb, acc3[n]);
    }
  }
  float enew[2][4];
  #pragma unroll
  for (int n = 0; n < 2; ++n){
    int col = nh*32 + n*16 + l15;
    float bv = b_e3[col];
    #pragma unroll
    for (int j = 0; j < 4; ++j){
      int r = mw*16 + lhi*4 + j;
      float v = acc3[n][j] + bv;
      enew[n][j] = v;
      long eg = (long)(ebase + r)*DD + col;
      e_out[eg] = has_resid ? (v + e_resid[eg]) : v;
      atomicAdd(&sEagg[sEb[r]*DD + col], v);
    }
  }
  __syncthreads();   // gemm3 reads of sA/sB complete

  // ---- A2 = concat[x_row, e_new]; stage n1_w1 ----
  #pragma unroll
  for (int n = 0; n < 2; ++n){
    #pragma unroll
    for (int j = 0; j < 4; ++j){
      int r = mw*16 + lhi*4 + j;
      st_h(sA, r, 64 + nh*32 + n*16 + l15, enew[n][j]);
    }
  }
  { int r = t >> 3, c = t & 7;
    pack16(sA, r, c, x_cur + (long)sRow[r]*DD + c*8); }
  stage_b(sB, w_n11, 128, 128, 0, t, 512);
  __syncthreads();

  // ---- GEMM4 ----
  f32x4 acc4[4];
  #pragma unroll
  for (int n = 0; n < 4; ++n) acc4[n] = f32x4{0.f,0.f,0.f,0.f};
  gemmN4(sA, sB, mw, nh, l15, lhi, acc4);
  __syncthreads();
  epiN4<true>(sH, acc4, b_n11, mw, nh, l15, lhi);
  stage_b(sB, w_n12, 128, 128, 0, t, 512);
  __syncthreads();

  // ---- GEMM5: SE ----
  f32x4 acc5[4];
  #pragma unroll
  for (int n = 0; n < 4; ++n) acc5[n] = f32x4{0.f,0.f,0.f,0.f};
  gemmN4(sH, sB, mw, nh, l15, lhi, acc5);

  if (CSR){
    epiN4<false>(sA, acc5, b_n12, mw, nh, l15, lhi);   // sA free since GEMM4
    __syncthreads();
    int r = t >> 3, oct = t & 7;
    long p = pos_arr[ebase + r];
    uint4v v0 = ld_chunk(sA, r, oct*2);
    uint4v v1 = ld_chunk(sA, r, oct*2 + 1);
    *(uint4v*)(se_buf + p*128 + oct*16) = v0;
    *(uint4v*)(se_buf + p*128 + oct*16 + 8) = v1;
  } else {
    #pragma unroll
    for (int n = 0; n < 4; ++n){
      int col = nh*64 + n*16 + l15;
      float bv = b_n12[col];
      #pragma unroll
      for (int j = 0; j < 4; ++j){
        int r = mw*16 + lhi*4 + j;
        atomicAdd(agg_sum + (long)sCol[r]*HH + col, acc5[n][j] + bv);
      }
    }
  }
  for (int i = t; i < NG*DD; i += 512) atomicAdd(e_agg + i, sEagg[i]);
}

// ---------------- node kernel: mean-gather + node-MLP2 ----------------
template<bool CSR>
__global__ __launch_bounds__(256, 2) void node_kernel(
    const float* __restrict__ x_cur, const float* __restrict__ u_cur,
    const float* __restrict__ x_resid, const int* __restrict__ batch,
    const ushort* __restrict__ se_buf, const int* __restrict__ deg,
    const int* __restrict__ off, const float* __restrict__ agg_sum,
    const ushort* __restrict__ w_n21, const ushort* __restrict__ w_n22,
    const float* __restrict__ b_n21, const float* __restrict__ b_n22,
    float* __restrict__ x_out, float* __restrict__ n_agg, int has_resid)
{
  __shared__ __align__(16) char sA[16384];
  __shared__ __align__(16) char sB[32768];
  __shared__ __align__(16) char sH[16384];
  __shared__ int sBat[64], sDeg[64], sOff[64];
  __shared__ float sRinv[64];
  __shared__ float sNagg[NG*DD];

  const int t = threadIdx.x;
  const int wv = t >> 6, ln = t & 63, l15 = ln & 15, lhi = ln >> 4;
  const int n0 = blockIdx.x * 64;

  if (t < 64){
    int nd = n0 + t;
    int ok = nd < N_NODES;
    sBat[t] = ok ? batch[nd] : 0;
    int d = ok ? deg[nd] : 0;
    sDeg[t] = d;
    sOff[t] = ok ? off[nd] : 0;
    sRinv[t] = 1.f / fmaxf((float)d, 1.f);
  }
  for (int i = t; i < NG*DD; i += 256) sNagg[i] = 0.f;
  __syncthreads();

  float s[32];
  const int r4 = t >> 2, q = t & 3;
  if (CSR){
    #pragma unroll
    for (int k = 0; k < 32; ++k) s[k] = 0.f;
    int d = sDeg[r4], o = sOff[r4];
    for (int i = 0; i < d; ++i){
      const ushort* src = se_buf + (long)(o + i)*HH + q*32;
      #pragma unroll
      for (int c = 0; c < 4; ++c){
        uint4v v = *(const uint4v*)(src + c*8);
        #pragma unroll
        for (int jj = 0; jj < 4; ++jj){
          s[c*8 + jj*2]     += bflo(v[jj]);
          s[c*8 + jj*2 + 1] += bfhi(v[jj]);
        }
      }
    }
    float riv = sRinv[r4];
    #pragma unroll
    for (int k = 0; k < 32; ++k) s[k] *= riv;
  }

  f32x4 acc[8];
  #pragma unroll
  for (int n = 0; n < 8; ++n) acc[n] = f32x4{0.f,0.f,0.f,0.f};

  for (int half = 0; half < 2; ++half){
    if (CSR){
      // dense part: x (half0, chunks 0-7) or u (half1, chunks 8-15)
      for (int task = t; task < 512; task += 256){
        int r = task >> 3, c = task & 7;
        int nd = n0 + r;
        bool ok = nd < N_NODES;
        float4 lo = {0,0,0,0}, hi = {0,0,0,0};
        if (ok){
          const float* src = (half == 0) ? (x_cur + (long)nd*DD + c*8)
                                         : (u_cur + (long)sBat[r]*DD + c*8);
          lo = *(const float4*)src; hi = *(const float4*)(src + 4);
        }
        uint4v v; v.x = pk2(lo.x, lo.y); v.y = pk2(lo.z, lo.w);
        v.z = pk2(hi.x, hi.y); v.w = pk2(hi.z, hi.w);
        st_chunk(sA, r, (half == 0) ? c : (8 + c), v);
      }
      // agg part from regs: half0 -> q<2 (agg cols 0..63), half1 -> q>=2 (cols 64..127)
      if ((half == 0 && q < 2) || (half == 1 && q >= 2)){
        int cbase = (half == 0) ? (8 + q*4) : ((q - 2)*4);
        #pragma unroll
        for (int cc = 0; cc < 4; ++cc){
          uint4v v;
          v.x = pk2(s[cc*8+0], s[cc*8+1]); v.y = pk2(s[cc*8+2], s[cc*8+3]);
          v.z = pk2(s[cc*8+4], s[cc*8+5]); v.w = pk2(s[cc*8+6], s[cc*8+7]);
          st_chunk(sA, r4, cbase + cc, v);
        }
      }
    } else {
      for (int task = t; task < 1024; task += 256){
        int r = task >> 4, c = task & 15;
        int nd = n0 + r;
        bool ok = nd < N_NODES;
        float scale = 1.f;
        const float* src;
        if (half == 0){
          if (c < 8) src = x_cur + (long)nd*DD + c*8;
          else { src = agg_sum + (long)nd*HH + (c-8)*8; scale = sRinv[r]; }
        } else {
          if (c < 8){ src = agg_sum + (long)nd*HH + 64 + c*8; scale = sRinv[r]; }
          else src = u_cur + (long)sBat[r]*DD + (c-8)*8;
        }
        float4 lo = {0,0,0,0}, hi = {0,0,0,0};
        if (ok){ lo = *(const float4*)src; hi = *(const float4*)(src + 4); }
        uint4v v; v.x = pk2(lo.x*scale, lo.y*scale); v.y = pk2(lo.z*scale, lo.w*scale);
        v.z = pk2(hi.x*scale, hi.y*scale); v.w = pk2(hi.z*scale, hi.w*scale);
        st_chunk(sA, r, c, v);
      }
    }
    stage_b(sB, w_n21, 128, 256, half*128, t, 256);
    __syncthreads();
    gemm_acc<8>(sA, sB, wv, l15, lhi, acc);
    __syncthreads();
  }
  epi_lds<8, true>(sH, acc, b_n21, wv, l15, lhi);
  stage_b(sB, w_n22, 64, 128, 0, t, 256);
  __syncthreads();

  f32x4 acc2[4];
  #pragma unroll
  for (int n = 0; n < 4; ++n) acc2[n] = f32x4{0.f,0.f,0.f,0.f};
  gemm_acc<4>(sH, sB, wv, l15, lhi, acc2);

  #pragma unroll
  for (int n = 0; n < 4; ++n){
    float bv = b_n22[n*16 + l15];
    #pragma unroll
    for (int j = 0; j < 4; ++j){
      int r = wv*16 + lhi*4 + j;
      int nd = n0 + r;
      if (nd < N_NODES){
        int col = n*16 + l15;
        float v = acc2[n][j] + bv;
        long xg = (long)nd*DD + col;
        x_out[xg] = has_resid ? (v + x_resid[xg]) : v;
        atomicAdd(&sNagg[sBat[r]*DD + col], v);
      }
    }
  }
  __syncthreads();
  for (int i = t; i < NG*DD; i += 256) atomicAdd(n_agg + i, sNagg[i]);
}

// ---------------- global (per-graph) MLP, fp32 ----------------
__global__ void global_kernel(const float* __restrict__ u_cur, const float* __restrict__ n_agg,
                              const float* __restrict__ e_agg, const float* __restrict__ cnt_b,
                              const float* __restrict__ cnt_e,
                              const float* __restrict__ g_w1, const float* __restrict__ g_b1,
                              const float* __restrict__ g_w2, const float* __restrict__ g_b2,
                              const float* __restrict__ u_resid, float* __restrict__ u_out,
                              int has_resid)
{
  int g = blockIdx.x, t = threadIdx.x;   // 192 threads
  __shared__ float uh[192];
  __shared__ float hb[128];
  float v;
  if (t < 64)       v = u_cur[g*64 + t];
  else if (t < 128) v = n_agg[g*64 + (t-64)] / fmaxf(cnt_b[g], 1.f);
  else              v = e_agg[g*64 + (t-128)] / fmaxf(cnt_e[g], 1.f);
  uh[t] = v;
  __syncthreads();
  if (t < 128){
    float s = g_b1[t];
    for (int k = 0; k < 192; ++k) s += uh[k] * g_w1[k*128 + t];
    hb[t] = fmaxf(s, 0.f);
  }
  __syncthreads();
  if (t < 64){
    float s = g_b2[t];
    for (int k = 0; k < 128; ++k) s += hb[k] * g_w2[k*64 + t];
    if (has_resid) s += u_resid[g*64 + t];
    u_out[g*64 + t] = s;
  }
}

extern "C" void kernel_launch(void* const* d_in, const int* in_sizes, int n_in,
                              void* d_out, int out_size, void* d_ws, size_t ws_size,
                              hipStream_t stream)
{
  const float* x0   = (const float*)d_in[0];
  const float* e0   = (const float*)d_in[1];
  const float* u0   = (const float*)d_in[2];
  const float* e_w1 = (const float*)d_in[3];
  const float* e_b1 = (const float*)d_in[4];
  const float* e_w2 = (const float*)d_in[5];
  const float* e_b2 = (const float*)d_in[6];
  const float* e_w3 = (const float*)d_in[7];
  const float* e_b3 = (const float*)d_in[8];
  const float* n1_w1 = (const float*)d_in[9];
  const float* n1_b1 = (const float*)d_in[10];
  const float* n1_w2 = (const float*)d_in[11];
  const float* n1_b2 = (const float*)d_in[12];
  const float* n2_w1 = (const float*)d_in[13];
  const float* n2_b1 = (const float*)d_in[14];
  const float* n2_w2 = (const float*)d_in[15];
  const float* n2_b2 = (const float*)d_in[16];
  const float* g_w1 = (const float*)d_in[17];
  const float* g_b1 = (const float*)d_in[18];
  const float* g_w2 = (const float*)d_in[19];
  const float* g_b2 = (const float*)d_in[20];
  const int* edge_index = (const int*)d_in[21];
  const int* batch      = (const int*)d_in[22];

  float* out_x = (float*)d_out;
  float* out_e = out_x + (long)N_NODES*DD;
  float* out_u = out_e + (long)E_EDGES*DD;

  char* ws = (char*)d_ws;
  int*   deg    = (int*)(ws + 0);            // 200,000
  int*   off    = (int*)(ws + 200000);       // 200,000
  int*   cursor = (int*)(ws + 400000);       // 200,000
  int*   bsum   = (int*)(ws + 600000);       // 256
  int*   bbase  = (int*)(ws + 600256);       // 256
  float* cnt_eb = (float*)(ws + 600512);     // 64
  float* cnt_b  = (float*)(ws + 600576);     // 64
  float* e_agg  = (float*)(ws + 600640);     // 4096
  float* n_agg  = (float*)(ws + 604736);     // 4096
  ushort* packed = (ushort*)(ws + 608832);   // 524,288 -> ends 1,133,120
  const size_t big = 1133120;
  bool use_csr = ws_size >= (size_t)(big + 204800000 + 3200000);
  ushort* se_buf = (ushort*)(ws + big);
  int*    pos    = (int*)(ws + big + 204800000);
  float*  agg_sum = (float*)(ws + big);      // fallback overlay (25.6 MB)

  (void)hipMemsetAsync(deg, 0, 200000, stream);
  (void)hipMemsetAsync(cnt_eb, 0, 128, stream);
  pack_weights<<<1024, 256, 0, stream>>>(e_w1, e_w2, e_w3, n1_w1, n1_w2, n2_w1, n2_w2, packed);
  hist_kernel<<<3125, 256, 0, stream>>>(edge_index, batch, deg, cnt_eb);
  count_nodes_kernel<<<196, 256, 0, stream>>>(batch, cnt_b);
  if (use_csr){
    scan_a<<<NB_SCAN, 1024, 0, stream>>>(deg, bsum);
    scan_b<<<1, 64, 0, stream>>>(bsum, bbase);
    scan_c<<<NB_SCAN, 1024, 0, stream>>>(deg, bbase, off, cursor);
    fill_kernel<<<3125, 256, 0, stream>>>(edge_index, cursor, pos);
  }

  const float* xc = x0;
  const float* ec = e0;
  const float* uc = u0;
  for (int l = 0; l < 2; ++l){
    (void)hipMemsetAsync(e_agg, 0, 8192, stream);   // e_agg + n_agg
    if (!use_csr)
      (void)hipMemsetAsync(agg_sum, 0, (size_t)N_NODES*HH*4, stream);
    const ushort* P = packed + (long)l*131072;
    if (use_csr){
      edge_kernel<true><<<E_EDGES/64, 512, 0, stream>>>(
          xc, ec, uc, e0, edge_index, batch, pos,
          P + 0, P + 32768, P + 49152, P + 57344, P + 73728,
          e_b1 + l*128, e_b2 + l*128, e_b3 + l*64, n1_b1 + l*128, n1_b2 + l*128,
          out_e, se_buf, agg_sum, e_agg, l == 1);
      node_kernel<true><<<782, 256, 0, stream>>>(
          xc, uc, x0, batch, se_buf, deg, off, agg_sum,
          P + 90112, P + 122880, n2_b1 + l*128, n2_b2 + l*64,
          out_x, n_agg, l == 1);
    } else {
      edge_kernel<false><<<E_EDGES/64, 512, 0, stream>>>(
          xc, ec, uc, e0, edge_index, batch, pos,
          P + 0, P + 32768, P + 49152, P + 57344, P + 73728,
          e_b1 + l*128, e_b2 + l*128, e_b3 + l*64, n1_b1 + l*128, n1_b2 + l*128,
          out_e, se_buf, agg_sum, e_agg, l == 1);
      node_kernel<false><<<782, 256, 0, stream>>>(
          xc, uc, x0, batch, se_buf, deg, off, agg_sum,
          P + 90112, P + 122880, n2_b1 + l*128, n2_b2 + l*64,
          out_x, n_agg, l == 1);
    }
    global_kernel<<<NG, 192, 0, stream>>>(
        uc, n_agg, e_agg, cnt_b, cnt_eb,
        g_w1 + l*192*128, g_b1 + l*128, g_w2 + l*128*64, g_b2 + l*64,
        u0, out_u, l == 1);
    xc = out_x; ec = out_e; uc = out_u;
  }
}